// Round 6
// baseline (222.184 us; speedup 1.0000x reference)
//
#include <hip/hip_runtime.h>
#include <hip/hip_bf16.h>

// Problem: B,W,H,L = 2,32,32,32 -> N=65536 voxels; D=512, E=64 heads, V=16.
// Round-17: R16's decode pipeline changed NOTHING (bench 210.7->210.9) =>
// decode-load scheduling is not the wall. Remaining structural costs of the
// per-(head,slice) decomposition: btg scanned 64x, W staged 16x/head, and
// Binomial head-skew stragglers (worst blocks 3-4x mean while most waves
// hold 0-1 tiles -> 30% occupancy, everything idle). Replace with two-phase
// bucketing via d_ws: phase A buckets voxel ids by head (LDS histogram, one
// atomicAdd per block-head, scatter); 1-wave directory prefix-scan; phase B
// = 1088 perfectly-balanced blocks, each 64 voxels of ONE head, W staged
// once, 4 waves x one 16-row MFMA tile with R16's pinned register pipeline.
#define DDIM 512
#define VDIM 16
#define EHEADS 64
#define NVOX 65536
#define KSTEPS 16                     // K=32 MFMA steps
#define QSTEP 4                       // k-steps per pipeline stage
#define GRPV 64                       // voxels per decode block
#define DECODE_BLOCKS (NVOX / GRPV + EHEADS)   // sum ceil(cnt/64) <= 1088

typedef __bf16  bf16x8  __attribute__((ext_vector_type(8)));
typedef float   floatx4 __attribute__((ext_vector_type(4)));

#define ISSUE_Q(LO, HI, Q)                                                  \
    _Pragma("unroll")                                                       \
    for (int k = 0; k < QSTEP; ++k) {                                       \
        const float* p = rowp + ((Q) * QSTEP + k) * 32;                     \
        LO[k] = *(const floatx4*)p;                                         \
        HI[k] = *(const floatx4*)(p + 4);                                   \
    }

#define COMPUTE_Q(LO, HI, Q)                                                \
    _Pragma("unroll")                                                       \
    for (int k = 0; k < QSTEP; ++k) {                                       \
        bf16x8 af;                                                          \
        _Pragma("unroll")                                                   \
        for (int j = 0; j < 4; ++j) {                                       \
            af[j]     = (__bf16)LO[k][j];                                   \
            af[4 + j] = (__bf16)HI[k][j];                                   \
        }                                                                   \
        acc = __builtin_amdgcn_mfma_f32_16x16x32_bf16(                      \
                  af, Wfrag[((Q) * QSTEP + k) * 64 + lane], acc, 0, 0, 0);  \
    }

// ---- Phase A: bucket voxel ids by head --------------------------------
__global__ __launch_bounds__(256) void bucket_kernel(
    const int* __restrict__ btg, const int* __restrict__ b2h,
    int* __restrict__ cursor, int* __restrict__ bucket, int capv)
{
    __shared__ int lut[256];
    __shared__ int hist[EHEADS];
    __shared__ int gbase[EHEADS];
    const int tid = threadIdx.x;
    lut[tid] = b2h[tid];
    if (tid < EHEADS) hist[tid] = 0;
    __syncthreads();
    const int n = blockIdx.x * 256 + tid;
    const int h = lut[btg[n]];
    const int lrank = atomicAdd(&hist[h], 1);     // local rank within block
    __syncthreads();
    if (tid < EHEADS)
        gbase[tid] = atomicAdd(&cursor[tid], hist[tid]);  // reserve range
    __syncthreads();
    const int pos = gbase[h] + lrank;
    if (pos < capv) bucket[h * capv + pos] = n;
}

// ---- Directory: per-head decode-block bases (1 wave, shfl prefix scan) --
__global__ __launch_bounds__(64) void directory_kernel(
    const int* __restrict__ cursor, int* __restrict__ blkbase, int capv)
{
    const int lane = threadIdx.x;                 // 64 threads
    int c = cursor[lane];
    if (c > capv) c = capv;
    int v = (c + GRPV - 1) / GRPV;
#pragma unroll
    for (int d = 1; d < 64; d <<= 1) {            // inclusive scan
        int u = __shfl_up(v, d);
        if (lane >= d) v += u;
    }
    blkbase[lane + 1] = v;
    if (lane == 0) blkbase[0] = 0;
}

// ---- Phase B: balanced decode, 64 voxels of one head per block ----------
__global__ __launch_bounds__(256, 4) void decode_kernel(
    const int* __restrict__ cursor, const int* __restrict__ blkbase,
    const int* __restrict__ bucket, int capv,
    const float* __restrict__ x, const float* __restrict__ Wh,
    const float* __restrict__ bh, float* __restrict__ out)
{
    __shared__ int    blk[EHEADS + 1];
    __shared__ bf16x8 Wfrag[KSTEPS * 64];         // 16 KB, MFMA fragment order

    const int tid  = threadIdx.x;
    const int lane = tid & 63;
    const int wv   = tid >> 6;
    const int m    = lane & 15;
    const int quad = lane >> 4;
    const int b    = blockIdx.x;

    if (tid <= EHEADS) blk[tid] = blkbase[tid];
    __syncthreads();
    if (b >= blk[EHEADS]) return;                 // uniform across block

    int lo = 0, hi = EHEADS;                      // blk[lo] <= b < blk[hi]
#pragma unroll
    for (int it = 0; it < 6; ++it) {
        const int mid = (lo + hi) >> 1;
        if (blk[mid] <= b) lo = mid; else hi = mid;
    }
    const int h = lo;
    const int j = b - blk[h];
    int cnth = cursor[h]; if (cnth > capv) cnth = capv;
    int nblk = cnth - j * GRPV; if (nblk > GRPV) nblk = GRPV;

    // Stage W[h] -> LDS fragment order; overlap with bucket-id load latency.
    floatx4 w0[4], w1[4];
#pragma unroll
    for (int i = 0; i < 4; ++i) {
        const int f  = i * 256 + tid;
        const int k0 = f >> 6, ln = f & 63;
        const float* src = Wh + ((size_t)h * VDIM + (ln & 15)) * DDIM
                              + k0 * 32 + (ln >> 4) * 8;
        w0[i] = *(const floatx4*)src;
        w1[i] = *(const floatx4*)(src + 4);
    }
    const int slot = wv * 16 + m;
    const int scl  = slot < nblk ? slot : nblk - 1;   // clamp (stores guarded)
    const int tbase = h * capv + j * GRPV;
    const int idx_m = bucket[tbase + scl];        // lane L holds row L&15
    const float bv  = bh[h * VDIM + m];
    __builtin_amdgcn_sched_barrier(0);            // all loads in flight

#pragma unroll
    for (int i = 0; i < 4; ++i) {
        bf16x8 bf;
#pragma unroll
        for (int jj = 0; jj < 4; ++jj) {
            bf[jj] = (__bf16)w0[i][jj]; bf[4 + jj] = (__bf16)w1[i][jj];
        }
        Wfrag[i * 256 + tid] = bf;
    }
    __syncthreads();

    if (wv * 16 >= nblk) return;                  // idle tail wave (no more barriers)

    const float* rowp = x + (size_t)idx_m * DDIM + (quad << 3);
    floatx4 acc = {0.f, 0.f, 0.f, 0.f};
    floatx4 alo[QSTEP], ahi[QSTEP], blo[QSTEP], bhi[QSTEP];

    ISSUE_Q(alo, ahi, 0)
    ISSUE_Q(blo, bhi, 1)
    __builtin_amdgcn_sched_barrier(0);
    COMPUTE_Q(alo, ahi, 0)
    __builtin_amdgcn_sched_barrier(0);
    ISSUE_Q(alo, ahi, 2)
    __builtin_amdgcn_sched_barrier(0);
    COMPUTE_Q(blo, bhi, 1)
    __builtin_amdgcn_sched_barrier(0);
    ISSUE_Q(blo, bhi, 3)
    __builtin_amdgcn_sched_barrier(0);
    COMPUTE_Q(alo, ahi, 2)
    __builtin_amdgcn_sched_barrier(0);
    COMPUTE_Q(blo, bhi, 3)

    // D: col = m (output v), row = quad*4 + r (voxel slot within tile)
#pragma unroll
    for (int r = 0; r < 4; ++r) {
        const int o = wv * 16 + quad * 4 + r;
        if (o < nblk) {
            const int vid = __shfl(idx_m, quad * 4 + r); // that slot's voxel
            out[(size_t)vid * VDIM + m] = acc[r] + bv;
        }
    }
}

extern "C" void kernel_launch(void* const* d_in, const int* in_sizes, int n_in,
                              void* d_out, int out_size, void* d_ws, size_t ws_size,
                              hipStream_t stream)
{
    const int*   btg = (const int*)d_in[0];
    const float* x   = (const float*)d_in[1];
    const float* Wh  = (const float*)d_in[2];
    const float* bh  = (const float*)d_in[3];
    const int*   b2h = (const int*)d_in[4];
    float*       out = (float*)d_out;
    (void)in_sizes; (void)n_in; (void)out_size;

    int*  cursor  = (int*)d_ws;                        // 64 ints
    int*  blkbase = (int*)((char*)d_ws + 1024);        // 65 ints
    int*  bucket  = (int*)((char*)d_ws + 4096);
    long long avail = ((long long)ws_size - 4096) / (EHEADS * 4);
    int capv = avail > NVOX ? NVOX : (avail < 0 ? 0 : (int)avail);

    hipMemsetAsync(d_ws, 0, 1024, stream);             // zero cursors (graph node)
    bucket_kernel<<<256, 256, 0, stream>>>(btg, b2h, cursor, bucket, capv);
    directory_kernel<<<1, 64, 0, stream>>>(cursor, blkbase, capv);
    decode_kernel<<<DECODE_BLOCKS, 256, 0, stream>>>(cursor, blkbase, bucket,
                                                     capv, x, Wh, bh, out);
}

// Round 7
// 217.349 us; speedup vs baseline: 1.0222x; 1.0222x over previous
//
#include <hip/hip_runtime.h>
#include <hip/hip_bf16.h>

// Problem: B,W,H,L = 2,32,32,32 -> N=65536 voxels; D=512, E=64 heads, V=16.
// Round-18: R17's bucketing regressed (+11 us) from execution overhead, not
// structure: extra directory launch, 1-voxel/thread phase A, and GRPV=64
// decode that restaged W per 64 voxels (34 MB W traffic) with 1 tile/wave.
// Lean rebuild: (1) directory fused into decode (wave-0 shfl scan of the 64
// L2-hot cursors per block, ~0.3 us); (2) phase A = 64 blocks, int4 btg,
// 4 voxels/thread, 4x fewer reserve atomics; (3) GRPV=128 -> 2 tiles/wave,
// W traffic ~18 MB, ~545 active blocks; id loads issued before W loads in
// the pinned prologue; launch_bounds(256,3) kills the spill risk.
#define DDIM 512
#define VDIM 16
#define EHEADS 64
#define NVOX 65536
#define KSTEPS 16                     // K=32 MFMA steps
#define QSTEP 4                       // k-steps per pipeline stage
#define GRPV 128                      // voxels per decode block (2 tiles/wave)
#define DECODE_BLOCKS (NVOX / GRPV + EHEADS)   // 512 + 64 = 576 >= sum ceil

typedef __bf16  bf16x8  __attribute__((ext_vector_type(8)));
typedef float   floatx4 __attribute__((ext_vector_type(4)));

#define ISSUE_Q(LO, HI, Q)                                                  \
    _Pragma("unroll")                                                       \
    for (int k = 0; k < QSTEP; ++k) {                                       \
        const float* p = rowp + ((Q) * QSTEP + k) * 32;                     \
        LO[k] = *(const floatx4*)p;                                         \
        HI[k] = *(const floatx4*)(p + 4);                                   \
    }

#define COMPUTE_Q(LO, HI, Q)                                                \
    _Pragma("unroll")                                                       \
    for (int k = 0; k < QSTEP; ++k) {                                       \
        bf16x8 af;                                                          \
        _Pragma("unroll")                                                   \
        for (int j = 0; j < 4; ++j) {                                       \
            af[j]     = (__bf16)LO[k][j];                                   \
            af[4 + j] = (__bf16)HI[k][j];                                   \
        }                                                                   \
        acc = __builtin_amdgcn_mfma_f32_16x16x32_bf16(                      \
                  af, Wfrag[((Q) * QSTEP + k) * 64 + lane], acc, 0, 0, 0);  \
    }

#define PIPELINE_TILE()                                                     \
    ISSUE_Q(alo, ahi, 0)                                                    \
    ISSUE_Q(blo, bhi, 1)                                                    \
    __builtin_amdgcn_sched_barrier(0);                                      \
    COMPUTE_Q(alo, ahi, 0)                                                  \
    __builtin_amdgcn_sched_barrier(0);                                      \
    ISSUE_Q(alo, ahi, 2)                                                    \
    __builtin_amdgcn_sched_barrier(0);                                      \
    COMPUTE_Q(blo, bhi, 1)                                                  \
    __builtin_amdgcn_sched_barrier(0);                                      \
    ISSUE_Q(blo, bhi, 3)                                                    \
    __builtin_amdgcn_sched_barrier(0);                                      \
    COMPUTE_Q(alo, ahi, 2)                                                  \
    __builtin_amdgcn_sched_barrier(0);                                      \
    COMPUTE_Q(blo, bhi, 3)

// ---- Phase A: bucket voxel ids by head (64 blocks, 4 voxels/thread) -----
__global__ __launch_bounds__(256) void bucket_kernel(
    const int* __restrict__ btg, const int* __restrict__ b2h,
    int* __restrict__ cursor, int* __restrict__ bucket, int capv)
{
    __shared__ int lut[256];
    __shared__ int hist[EHEADS];
    __shared__ int gbase[EHEADS];
    const int tid = threadIdx.x;
    lut[tid] = b2h[tid];
    if (tid < EHEADS) hist[tid] = 0;
    __syncthreads();
    const int base = blockIdx.x * 1024 + tid * 4;
    const int4 bt = *(const int4*)(btg + base);
    const int h0 = lut[bt.x], h1 = lut[bt.y], h2 = lut[bt.z], h3 = lut[bt.w];
    const int r0 = atomicAdd(&hist[h0], 1);
    const int r1 = atomicAdd(&hist[h1], 1);
    const int r2 = atomicAdd(&hist[h2], 1);
    const int r3 = atomicAdd(&hist[h3], 1);
    __syncthreads();
    if (tid < EHEADS)
        gbase[tid] = atomicAdd(&cursor[tid], hist[tid]);  // reserve range
    __syncthreads();
    int p;
    p = gbase[h0] + r0; if (p < capv) bucket[h0 * capv + p] = base;
    p = gbase[h1] + r1; if (p < capv) bucket[h1 * capv + p] = base + 1;
    p = gbase[h2] + r2; if (p < capv) bucket[h2 * capv + p] = base + 2;
    p = gbase[h3] + r3; if (p < capv) bucket[h3 * capv + p] = base + 3;
}

// ---- Phase B: balanced decode, 128 voxels of one head per block ---------
__global__ __launch_bounds__(256, 3) void decode_kernel(
    const int* __restrict__ cursor, const int* __restrict__ bucket, int capv,
    const float* __restrict__ x, const float* __restrict__ Wh,
    const float* __restrict__ bh, float* __restrict__ out)
{
    __shared__ int    blk[EHEADS + 1];
    __shared__ bf16x8 Wfrag[KSTEPS * 64];         // 16 KB, MFMA fragment order

    const int tid  = threadIdx.x;
    const int lane = tid & 63;
    const int wv   = tid >> 6;
    const int m    = lane & 15;
    const int quad = lane >> 4;
    const int b    = blockIdx.x;

    // In-block directory: prefix scan of ceil(cnt/GRPV) over 64 heads.
    if (wv == 0) {
        int c = cursor[lane];
        if (c > capv) c = capv;
        int v = (c + GRPV - 1) >> 7;              // GRPV = 128
#pragma unroll
        for (int d = 1; d < 64; d <<= 1) {
            const int u = __shfl_up(v, d);
            if (lane >= d) v += u;
        }
        blk[lane + 1] = v;
        if (lane == 0) blk[0] = 0;
    }
    __syncthreads();
    if (b >= blk[EHEADS]) return;                 // uniform across block

    int lo = 0, hi = EHEADS;                      // blk[lo] <= b < blk[hi]
#pragma unroll
    for (int it = 0; it < 6; ++it) {
        const int mid = (lo + hi) >> 1;
        if (blk[mid] <= b) lo = mid; else hi = mid;
    }
    const int h = lo;
    const int j = b - blk[h];
    int cnth = cursor[h]; if (cnth > capv) cnth = capv;
    int nblk = cnth - j * GRPV; if (nblk > GRPV) nblk = GRPV;
    const int tb = h * capv + j * GRPV;

    // Pinned prologue: bucket ids first (x-gather critical path), then W.
    const int s0 = wv * 32 + m;
    const int c0 = s0 < nblk ? s0 : nblk - 1;     // clamp (stores guarded)
    const int c1 = s0 + 16 < nblk ? s0 + 16 : nblk - 1;
    const int id0 = bucket[tb + c0];              // tile 0: lane holds row m
    const int id1 = bucket[tb + c1];              // tile 1
    floatx4 w0[4], w1[4];
#pragma unroll
    for (int i = 0; i < 4; ++i) {
        const int f  = i * 256 + tid;
        const int k0 = f >> 6, ln = f & 63;
        const float* src = Wh + ((size_t)h * VDIM + (ln & 15)) * DDIM
                              + k0 * 32 + (ln >> 4) * 8;
        w0[i] = *(const floatx4*)src;
        w1[i] = *(const floatx4*)(src + 4);
    }
    __builtin_amdgcn_sched_barrier(0);            // all loads in flight

#pragma unroll
    for (int i = 0; i < 4; ++i) {
        bf16x8 bf;
#pragma unroll
        for (int jj = 0; jj < 4; ++jj) {
            bf[jj] = (__bf16)w0[i][jj]; bf[4 + jj] = (__bf16)w1[i][jj];
        }
        Wfrag[i * 256 + tid] = bf;
    }
    __syncthreads();

    if (wv * 32 >= nblk) return;                  // idle tail wave

    const float bv = bh[h * VDIM + m];
    floatx4 alo[QSTEP], ahi[QSTEP], blo[QSTEP], bhi[QSTEP];

    // ---- Tile 0 ----
    const float* rowp = x + (size_t)id0 * DDIM + (quad << 3);
    floatx4 acc = {0.f, 0.f, 0.f, 0.f};
    PIPELINE_TILE()
#pragma unroll
    for (int r = 0; r < 4; ++r) {
        const int o = wv * 32 + quad * 4 + r;
        if (o < nblk) {
            const int vid = __shfl(id0, quad * 4 + r);
            out[(size_t)vid * VDIM + m] = acc[r] + bv;
        }
    }

    // ---- Tile 1 ----
    rowp = x + (size_t)id1 * DDIM + (quad << 3);
    acc = (floatx4){0.f, 0.f, 0.f, 0.f};
    PIPELINE_TILE()
#pragma unroll
    for (int r = 0; r < 4; ++r) {
        const int o = wv * 32 + 16 + quad * 4 + r;
        if (o < nblk) {
            const int vid = __shfl(id1, quad * 4 + r);
            out[(size_t)vid * VDIM + m] = acc[r] + bv;
        }
    }
}

extern "C" void kernel_launch(void* const* d_in, const int* in_sizes, int n_in,
                              void* d_out, int out_size, void* d_ws, size_t ws_size,
                              hipStream_t stream)
{
    const int*   btg = (const int*)d_in[0];
    const float* x   = (const float*)d_in[1];
    const float* Wh  = (const float*)d_in[2];
    const float* bh  = (const float*)d_in[3];
    const int*   b2h = (const int*)d_in[4];
    float*       out = (float*)d_out;
    (void)in_sizes; (void)n_in; (void)out_size;

    int* cursor = (int*)d_ws;                          // 64 ints
    int* bucket = (int*)((char*)d_ws + 4096);
    long long avail = ((long long)ws_size - 4096) / (EHEADS * 4);
    int capv = avail > NVOX ? NVOX : (avail < 0 ? 0 : (int)avail);

    hipMemsetAsync(d_ws, 0, 256, stream);              // zero cursors
    bucket_kernel<<<64, 256, 0, stream>>>(btg, b2h, cursor, bucket, capv);
    decode_kernel<<<DECODE_BLOCKS, 256, 0, stream>>>(cursor, bucket, capv,
                                                     x, Wh, bh, out);
}

// Round 8
// 212.938 us; speedup vs baseline: 1.0434x; 1.0207x over previous
//
#include <hip/hip_runtime.h>
#include <hip/hip_bf16.h>

// Problem: B,W,H,L = 2,32,32,32 -> N=65536 voxels; D=512, E=64 heads, V=16.
// Round-19: bucketing experiments (R17 +11, R18 +6.4 vs R16) prove the
// decomposition is not the wall — the shared decode path is. R15's flat
// 16-deep issue spilled (128 live load regs under a 128-reg launch_bounds
// cap); R16's rolling 2x4 avoided spill but keeps only 8 loads/wave in
// flight and pays 2 serial HBM latencies per tile. This round: flat 32-deep
// issue (whole tile = ONE latency, progressive vmcnt(30..) lets early
// k-steps' cvt+MFMA overlap tail loads) under __launch_bounds__(256,3)
// (VGPR cap ~170 -> 128 live load regs + ~25 overhead fit, zero spill).
// 12 waves/CU but 192 KB/CU in flight (vs 128 KB at R16's 16 waves).
#define DDIM 512
#define VDIM 16
#define EHEADS 64
#define NVOX 65536
#define QPERH 16
#define SLICE (NVOX / QPERH)          // 4096 voxels per block slice
#define NBLOCKS (EHEADS * QPERH)      // 1024 blocks
#define WRANGE (SLICE / 4)            // 1024 voxels per wave
#define WCAP 256                      // per-wave list cap (mean ~16, >25 sigma)
#define KSTEPS 16                     // K=32 MFMA steps

typedef __bf16  bf16x8  __attribute__((ext_vector_type(8)));
typedef float   floatx4 __attribute__((ext_vector_type(4)));

__global__ __launch_bounds__(256, 3) void fused_decode_kernel(
    const int*   __restrict__ btg,   // (NVOX,)
    const int*   __restrict__ b2h,   // (256,)
    const float* __restrict__ x,     // (NVOX, D)
    const float* __restrict__ Wh,    // (E, V, D)
    const float* __restrict__ bh,    // (E, V)
    float*       __restrict__ out)   // (NVOX, V)
{
    __shared__ int    lut[256];                   // 1 KB
    __shared__ bf16x8 Wfrag[KSTEPS * 64];         // 16 KB, MFMA fragment order
    __shared__ int    wlist[4][WCAP];             // 4 KB, per-wave lists

    const int tid  = threadIdx.x;
    const int lane = tid & 63;
    const int wv   = tid >> 6;                    // wave in block (0..3)
    const int e    = blockIdx.x >> 4;             // head
    const int q    = blockIdx.x & (QPERH - 1);    // slice
    const int m    = lane & 15;
    const int quad = lane >> 4;

    lut[tid] = b2h[tid];

    // ---- Prologue: issue W-tile AND btg loads, then convert/stage ---------
    // Wfrag[k0*64 + ln] = W[e][ln&15][k0*32 + (ln>>4)*8 + j], j=0..7
    floatx4 w0[4], w1[4];
#pragma unroll
    for (int i = 0; i < 4; ++i) {
        const int f  = i * 256 + tid;
        const int k0 = f >> 6, ln = f & 63;
        const float* src = Wh + ((size_t)e * VDIM + (ln & 15)) * DDIM
                              + k0 * 32 + (ln >> 4) * 8;
        w0[i] = *(const floatx4*)src;
        w1[i] = *(const floatx4*)(src + 4);
    }
    const int wbase = q * SLICE + wv * WRANGE;
    int bt[WRANGE / 64];
#pragma unroll
    for (int i = 0; i < WRANGE / 64; ++i)         // 16 independent loads
        bt[i] = btg[wbase + i * 64 + lane];
    __builtin_amdgcn_sched_barrier(0);            // all 24 loads in flight

#pragma unroll
    for (int i = 0; i < 4; ++i) {                 // waits W only
        bf16x8 bf;
#pragma unroll
        for (int j = 0; j < 4; ++j) {
            bf[j] = (__bf16)w0[i][j]; bf[4 + j] = (__bf16)w1[i][j];
        }
        Wfrag[i * 256 + tid] = bf;
    }
    __syncthreads();                              // ONLY barrier in the kernel

    // ---- Per-wave atomic-free scan: ballot prefix on preloaded bt[] -------
    int cnt = 0;
#pragma unroll
    for (int i = 0; i < WRANGE / 64; ++i) {
        const bool match = (lut[bt[i]] == e);
        const unsigned long long mk = __ballot(match);
        if (match) {
            const int p = cnt + __popcll(mk & ((1ull << lane) - 1ull));
            if (p < WCAP) wlist[wv][p] = wbase + i * 64 + lane;
        }
        cnt += __popcll(mk);
    }
    if (cnt > WCAP) cnt = WCAP;

    const float bv = bh[e * VDIM + m];
    const int ntiles = (cnt + 15) >> 4;

    // ---- Decode: flat 32-deep register gather, schedule pinned ------------
    // A-fragment for lane l, kstep k: row (l&15), cols k*32 + (l>>4)*8 .. +8
    for (int t = 0; t < ntiles; ++t) {
        const int rs = t * 16;
        int rm = rs + m;
        if (rm >= cnt) rm = cnt - 1;              // clamp tail (stores guarded)
        const int idx_m = wlist[wv][rm];          // lane L holds row L&15
        const float* rowp = x + (size_t)idx_m * DDIM + (quad << 3);

        floatx4 acc = {0.f, 0.f, 0.f, 0.f};
        floatx4 ra[KSTEPS], rb[KSTEPS];
#pragma unroll
        for (int k = 0; k < KSTEPS; ++k) {        // 32 independent dwordx4
            const float* p = rowp + k * 32;
            ra[k] = *(const floatx4*)p;
            rb[k] = *(const floatx4*)(p + 4);
        }
        __builtin_amdgcn_sched_barrier(0);        // ONE latency for the tile
#pragma unroll
        for (int k = 0; k < KSTEPS; ++k) {        // progressive vmcnt(30..0)
            bf16x8 af;
#pragma unroll
            for (int j = 0; j < 4; ++j) {
                af[j]     = (__bf16)ra[k][j];
                af[4 + j] = (__bf16)rb[k][j];
            }
            acc = __builtin_amdgcn_mfma_f32_16x16x32_bf16(
                      af, Wfrag[k * 64 + lane], acc, 0, 0, 0);
        }

        // D: col = m (output v), row = quad*4 + r (voxel within tile)
#pragma unroll
        for (int r = 0; r < 4; ++r) {
            const int o = rs + quad * 4 + r;
            if (o < cnt)
                out[(size_t)wlist[wv][o] * VDIM + m] = acc[r] + bv;
        }
    }
}

extern "C" void kernel_launch(void* const* d_in, const int* in_sizes, int n_in,
                              void* d_out, int out_size, void* d_ws, size_t ws_size,
                              hipStream_t stream)
{
    const int*   btg = (const int*)d_in[0];
    const float* x   = (const float*)d_in[1];
    const float* Wh  = (const float*)d_in[2];
    const float* bh  = (const float*)d_in[3];
    const int*   b2h = (const int*)d_in[4];
    float*       out = (float*)d_out;
    (void)d_ws; (void)ws_size; (void)in_sizes; (void)n_in; (void)out_size;

    fused_decode_kernel<<<NBLOCKS, 256, 0, stream>>>(btg, b2h, x, Wh, bh, out);
}

// Round 9
// 212.663 us; speedup vs baseline: 1.0448x; 1.0013x over previous
//
#include <hip/hip_runtime.h>
#include <hip/hip_bf16.h>

// Problem: B,W,H,L = 2,32,32,32 -> N=65536 voxels; D=512, E=64 heads, V=16.
// Round-20: 4 null results (pin/roll/bucket/flat-32-deep) + R11/R12 counters
// say the gather PATTERN is the wall: 16 scattered rows x 128 B per
// instruction -> ~40K fine-grained streams chip-wide -> DRAM row thrash ->
// 1.4 TB/s, while the harness fill streams at 7 TB/s with 3 waves/CU.
// This round decouples load layout from fragment layout: load each x-row as
// a whole-row burst (64 lanes x 16 B = 1 KB/instr, 2 instr per 2 KB row, ONE
// stream per wave), cvt to bf16, redistribute via per-wave XOR-swizzled LDS
// (8 rows/half = 8 KB/wave; 53 KB total -> 3 blocks/CU), MFMA reads swizzled
// ds_read_b128. Tile = 2 halves with split accumulators (A-rows 0-7 in acc1,
// 8-15 in acc2, zeros elsewhere); store selects acc by quad.
#define DDIM 512
#define VDIM 16
#define EHEADS 64
#define NVOX 65536
#define QPERH 16
#define SLICE (NVOX / QPERH)          // 4096 voxels per block slice
#define NBLOCKS (EHEADS * QPERH)      // 1024 blocks
#define WRANGE (SLICE / 4)            // 1024 voxels per wave
#define WCAP 256                      // per-wave list cap (mean ~16, >25 sigma)
#define KSTEPS 16                     // K=32 MFMA steps

typedef __bf16  bf16x8  __attribute__((ext_vector_type(8)));
typedef __bf16  bf16x4  __attribute__((ext_vector_type(4)));
typedef float   floatx4 __attribute__((ext_vector_type(4)));

// Issue 8 whole-row burst loads (rows H*8 .. H*8+7), 2 x dwordx4 per row.
#define LOAD_HALF(H)                                                        \
    _Pragma("unroll")                                                       \
    for (int r = 0; r < 8; ++r) {                                           \
        const int row = (H) * 8 + r;                                        \
        const int idx = __shfl(idx_m, row);                                 \
        const char* rp = (const char*)x + (size_t)idx * 2048 + lane * 16;   \
        g0[r] = *(const floatx4*)rp;                                        \
        g1[r] = *(const floatx4*)(rp + 1024);                               \
    }

// Convert the 8 staged rows to bf16 and write them XOR-swizzled into the
// wave's LDS row buffer. Lane holds floats [lane*4,+4) and [256+lane*4,+4).
#define WRITE_HALF()                                                        \
    _Pragma("unroll")                                                       \
    for (int r = 0; r < 8; ++r) {                                           \
        bf16x4 b0, b1;                                                      \
        _Pragma("unroll")                                                   \
        for (int j = 0; j < 4; ++j) {                                       \
            b0[j] = (__bf16)g0[r][j]; b1[j] = (__bf16)g1[r][j];             \
        }                                                                   \
        char* wb = myrow + r * 1024;                                        \
        *(bf16x4*)(wb + ((lane * 8) ^ (r << 4)))       = b0;                \
        *(bf16x4*)(wb + ((512 + lane * 8) ^ (r << 4))) = b1;                \
    }

__global__ __launch_bounds__(256, 3) void fused_decode_kernel(
    const int*   __restrict__ btg,   // (NVOX,)
    const int*   __restrict__ b2h,   // (256,)
    const float* __restrict__ x,     // (NVOX, D)
    const float* __restrict__ Wh,    // (E, V, D)
    const float* __restrict__ bh,    // (E, V)
    float*       __restrict__ out)   // (NVOX, V)
{
    __shared__ int    lut[256];                   // 1 KB
    __shared__ bf16x8 Wfrag[KSTEPS * 64];         // 16 KB, MFMA fragment order
    __shared__ int    wlist[4][WCAP];             // 4 KB, per-wave lists
    __shared__ __align__(16) char rowbuf[4][8192];// 32 KB, per-wave 8-row bf16

    const int tid  = threadIdx.x;
    const int lane = tid & 63;
    const int wv   = tid >> 6;                    // wave in block (0..3)
    const int e    = blockIdx.x >> 4;             // head
    const int q    = blockIdx.x & (QPERH - 1);    // slice
    const int m    = lane & 15;
    const int quad = lane >> 4;

    lut[tid] = b2h[tid];

    // ---- Prologue: issue W-tile AND btg loads, then convert/stage ---------
    // Wfrag[k0*64 + ln] = W[e][ln&15][k0*32 + (ln>>4)*8 + j], j=0..7
    floatx4 w0[4], w1[4];
#pragma unroll
    for (int i = 0; i < 4; ++i) {
        const int f  = i * 256 + tid;
        const int k0 = f >> 6, ln = f & 63;
        const float* src = Wh + ((size_t)e * VDIM + (ln & 15)) * DDIM
                              + k0 * 32 + (ln >> 4) * 8;
        w0[i] = *(const floatx4*)src;
        w1[i] = *(const floatx4*)(src + 4);
    }
    const int wbase = q * SLICE + wv * WRANGE;
    int bt[WRANGE / 64];
#pragma unroll
    for (int i = 0; i < WRANGE / 64; ++i)         // 16 independent loads
        bt[i] = btg[wbase + i * 64 + lane];
    __builtin_amdgcn_sched_barrier(0);            // all 24 loads in flight

#pragma unroll
    for (int i = 0; i < 4; ++i) {                 // waits W only
        bf16x8 bf;
#pragma unroll
        for (int j = 0; j < 4; ++j) {
            bf[j] = (__bf16)w0[i][j]; bf[4 + j] = (__bf16)w1[i][j];
        }
        Wfrag[i * 256 + tid] = bf;
    }
    __syncthreads();                              // ONLY barrier in the kernel

    // ---- Per-wave atomic-free scan: ballot prefix on preloaded bt[] -------
    int cnt = 0;
#pragma unroll
    for (int i = 0; i < WRANGE / 64; ++i) {
        const bool match = (lut[bt[i]] == e);
        const unsigned long long mk = __ballot(match);
        if (match) {
            const int p = cnt + __popcll(mk & ((1ull << lane) - 1ull));
            if (p < WCAP) wlist[wv][p] = wbase + i * 64 + lane;
        }
        cnt += __popcll(mk);
    }
    if (cnt > WCAP) cnt = WCAP;

    const float bv = bh[e * VDIM + m];
    const int ntiles = (cnt + 15) >> 4;
    char* const myrow = rowbuf[wv];

    // ---- Decode: whole-row burst loads -> swizzled LDS -> MFMA ------------
    for (int t = 0; t < ntiles; ++t) {
        const int rs = t * 16;
        int rm = rs + m;
        if (rm >= cnt) rm = cnt - 1;              // clamp tail (stores guarded)
        const int idx_m = wlist[wv][rm];          // lane L holds row L&15

        floatx4 acc1 = {0.f, 0.f, 0.f, 0.f};     // A rows 0-7 (quads 0-1 valid)
        floatx4 acc2 = {0.f, 0.f, 0.f, 0.f};     // A rows 8-15 (quads 2-3 valid)
        floatx4 g0[8], g1[8];

        LOAD_HALF(0)                              // rows 0-7 in flight
        __builtin_amdgcn_sched_barrier(0);
        WRITE_HALF()                              // cvt+LDS (drains half 0)
        LOAD_HALF(1)                              // rows 8-15 in flight
        __builtin_amdgcn_sched_barrier(0);

        // acc1 MFMAs on half 0 overlap half-1's HBM flight.
#pragma unroll
        for (int k = 0; k < KSTEPS; ++k) {
            bf16x8 a1;
#pragma unroll
            for (int j = 0; j < 8; ++j) a1[j] = (__bf16)0.f;
            if (m < 8)
                a1 = *(const bf16x8*)(myrow + m * 1024
                                      + ((quad * 16 + k * 64) ^ (m << 4)));
            acc1 = __builtin_amdgcn_mfma_f32_16x16x32_bf16(
                       a1, Wfrag[k * 64 + lane], acc1, 0, 0, 0);
        }
        __builtin_amdgcn_sched_barrier(0);
        WRITE_HALF()                              // rows 8-15 -> LDS
#pragma unroll
        for (int k = 0; k < KSTEPS; ++k) {
            bf16x8 a2;
#pragma unroll
            for (int j = 0; j < 8; ++j) a2[j] = (__bf16)0.f;
            if (m >= 8)
                a2 = *(const bf16x8*)(myrow + (m - 8) * 1024
                                      + ((quad * 16 + k * 64) ^ ((m - 8) << 4)));
            acc2 = __builtin_amdgcn_mfma_f32_16x16x32_bf16(
                       a2, Wfrag[k * 64 + lane], acc2, 0, 0, 0);
        }

        // D: col = m (output v), row = quad*4 + r; pick acc by quad.
#pragma unroll
        for (int r = 0; r < 4; ++r) {
            const int o = rs + quad * 4 + r;
            const float val = (quad < 2) ? acc1[r] : acc2[r];
            if (o < cnt)
                out[(size_t)wlist[wv][o] * VDIM + m] = val + bv;
        }
    }
}

extern "C" void kernel_launch(void* const* d_in, const int* in_sizes, int n_in,
                              void* d_out, int out_size, void* d_ws, size_t ws_size,
                              hipStream_t stream)
{
    const int*   btg = (const int*)d_in[0];
    const float* x   = (const float*)d_in[1];
    const float* Wh  = (const float*)d_in[2];
    const float* bh  = (const float*)d_in[3];
    const int*   b2h = (const int*)d_in[4];
    float*       out = (float*)d_out;
    (void)d_ws; (void)ws_size; (void)in_sizes; (void)n_in; (void)out_size;

    fused_decode_kernel<<<NBLOCKS, 256, 0, stream>>>(btg, b2h, x, Wh, bh, out);
}